// Round 1
// baseline (794.449 us; speedup 1.0000x reference)
//
#include <hip/hip_runtime.h>
#include <hip/hip_bf16.h>
#include <math.h>

#define DDIM 256
#define NSEG 128

// Monotonic uint encoding of float for atomicMax (init 0 < key(-inf)=0x007FFFFF).
__device__ __forceinline__ unsigned float_key(float f) {
  unsigned u = __float_as_uint(f);
  return (u & 0x80000000u) ? ~u : (u | 0x80000000u);
}
__device__ __forceinline__ float key_float(unsigned u) {
  return __uint_as_float((u & 0x80000000u) ? (u & 0x7FFFFFFFu) : ~u);
}

// ws layout (bytes):
//   0    : float ws_vecs[514]  -> wk_sum[256], wvo[256], {bk_sum, bvo}
//   4096 : unsigned segmax[128]
//   4608 : float segsum[128]
//   5120 : float segwv[128]
//   8192 : float lbuf[N]; float vbuf[N]   (fast path only)

__global__ __launch_bounds__(256) void prep_kernel(
    const float* __restrict__ Wk, const float* __restrict__ bk,
    const float* __restrict__ Wv, const float* __restrict__ bv,
    const float* __restrict__ Wo,
    float* __restrict__ ws_vecs, unsigned* __restrict__ segmax,
    float* __restrict__ segsum, float* __restrict__ segwv) {
  const int d = threadIdx.x;  // 0..255
  // Row sums: wk_sum[d] = sum_e Wk[d,e]; wvo[d] = sum_e Wv[d,e]*Wo[e]
  const float4* wkr = (const float4*)(Wk + (size_t)d * DDIM);
  const float4* wvr = (const float4*)(Wv + (size_t)d * DDIM);
  const float4* wo4 = (const float4*)Wo;
  float s1 = 0.f, s2 = 0.f;
  #pragma unroll 4
  for (int e4 = 0; e4 < DDIM / 4; ++e4) {
    float4 a = wkr[e4];
    float4 b = wvr[e4];
    float4 w = wo4[e4];
    s1 += a.x + a.y + a.z + a.w;
    s2 += b.x * w.x + b.y * w.y + b.z * w.z + b.w * w.w;
  }
  ws_vecs[d] = s1;
  ws_vecs[DDIM + d] = s2;

  // Block-reduce bk_sum and bvo = sum_e bv[e]*Wo[e]
  __shared__ float r1[256], r2[256];
  r1[d] = bk[d];
  r2[d] = bv[d] * Wo[d];
  __syncthreads();
  for (int off = 128; off > 0; off >>= 1) {
    if (d < off) { r1[d] += r1[d + off]; r2[d] += r2[d + off]; }
    __syncthreads();
  }
  if (d == 0) { ws_vecs[2 * DDIM] = r1[0]; ws_vecs[2 * DDIM + 1] = r2[0]; }

  // Init accumulators (ws is re-poisoned 0xAA before every timed call)
  if (d < NSEG) { segmax[d] = 0u; segsum[d] = 0.f; segwv[d] = 0.f; }
}

// Pass 1: one wave handles rowsPerWave contiguous rows. Lane l owns x[row, 4l..4l+3].
// Computes l[n] = x.wk_sum + bk_sum, v[n] = x.wvo + bvo; tracks per-run segment max.
template <bool STORE>
__global__ __launch_bounds__(256) void pass1_kernel(
    const float* __restrict__ x, const int* __restrict__ seg,
    const float* __restrict__ ws_vecs,
    float* __restrict__ lbuf, float* __restrict__ vbuf,
    unsigned* __restrict__ segmax, int nrows, int rowsPerWave) {
  const int lane = threadIdx.x & 63;
  const int wave = (blockIdx.x * blockDim.x + threadIdx.x) >> 6;
  const float4 wk4 = ((const float4*)ws_vecs)[lane];
  const float4 wv4 = ((const float4*)(ws_vecs + DDIM))[lane];
  const float bk_sum = ws_vecs[2 * DDIM];
  const float bvo = ws_vecs[2 * DDIM + 1];

  const int row0 = wave * rowsPerWave;
  const int row1 = min(row0 + rowsPerWave, nrows);

  int cur_seg = -1;
  float cur_max = 0.f;
  for (int row = row0; row < row1; ++row) {
    const float4 x4 = ((const float4*)(x + (size_t)row * DDIM))[lane];
    float dk = x4.x * wk4.x + x4.y * wk4.y + x4.z * wk4.z + x4.w * wk4.w;
    float dv = x4.x * wv4.x + x4.y * wv4.y + x4.z * wv4.z + x4.w * wv4.w;
    #pragma unroll
    for (int off = 32; off; off >>= 1) {
      dk += __shfl_xor(dk, off);
      dv += __shfl_xor(dv, off);
    }
    if (lane == 0) {
      const float l = dk + bk_sum;
      if (STORE) { lbuf[row] = l; vbuf[row] = dv + bvo; }
      const int s = seg[row];
      if (s != cur_seg) {
        if (cur_seg >= 0) atomicMax(&segmax[cur_seg], float_key(cur_max));
        cur_seg = s;
        cur_max = l;
      } else {
        cur_max = fmaxf(cur_max, l);
      }
    }
  }
  if (lane == 0 && cur_seg >= 0) atomicMax(&segmax[cur_seg], float_key(cur_max));
}

// Pass 2 (fast path): exp + segmented sums from the l/v buffers.
__global__ __launch_bounds__(256) void pass2_kernel(
    const float* __restrict__ lbuf, const float* __restrict__ vbuf,
    const int* __restrict__ seg, const unsigned* __restrict__ segmax,
    float* __restrict__ segsum, float* __restrict__ segwv, int nrows) {
  const int gid = blockIdx.x * blockDim.x + threadIdx.x;
  const int lane = threadIdx.x & 63;
  float ex = 0.f, exv = 0.f;
  int s = -1;
  if (gid < nrows) {
    s = seg[gid];
    const float m = key_float(segmax[s]);
    ex = expf(lbuf[gid] - m);
    exv = ex * vbuf[gid];
  }
  const int s0 = __shfl(s, 0);
  const bool uni = __all(s == s0);
  if (uni && s0 >= 0) {
    #pragma unroll
    for (int off = 32; off; off >>= 1) {
      ex += __shfl_xor(ex, off);
      exv += __shfl_xor(exv, off);
    }
    if (lane == 0) {
      atomicAdd(&segsum[s0], ex);
      atomicAdd(&segwv[s0], exv);
    }
  } else if (s >= 0) {
    atomicAdd(&segsum[s], ex);
    atomicAdd(&segwv[s], exv);
  }
}

// Pass 2 (fallback, no scratch): recompute dots from x, then accumulate.
__global__ __launch_bounds__(256) void pass2_recompute_kernel(
    const float* __restrict__ x, const int* __restrict__ seg,
    const float* __restrict__ ws_vecs, const unsigned* __restrict__ segmax,
    float* __restrict__ segsum, float* __restrict__ segwv,
    int nrows, int rowsPerWave) {
  const int lane = threadIdx.x & 63;
  const int wave = (blockIdx.x * blockDim.x + threadIdx.x) >> 6;
  const float4 wk4 = ((const float4*)ws_vecs)[lane];
  const float4 wv4 = ((const float4*)(ws_vecs + DDIM))[lane];
  const float bk_sum = ws_vecs[2 * DDIM];
  const float bvo = ws_vecs[2 * DDIM + 1];

  const int row0 = wave * rowsPerWave;
  const int row1 = min(row0 + rowsPerWave, nrows);

  int cur_seg = -1;
  float se = 0.f, sev = 0.f;
  for (int row = row0; row < row1; ++row) {
    const float4 x4 = ((const float4*)(x + (size_t)row * DDIM))[lane];
    float dk = x4.x * wk4.x + x4.y * wk4.y + x4.z * wk4.z + x4.w * wk4.w;
    float dv = x4.x * wv4.x + x4.y * wv4.y + x4.z * wv4.z + x4.w * wv4.w;
    #pragma unroll
    for (int off = 32; off; off >>= 1) {
      dk += __shfl_xor(dk, off);
      dv += __shfl_xor(dv, off);
    }
    if (lane == 0) {
      const float l = dk + bk_sum;
      const float v = dv + bvo;
      const int s = seg[row];
      const float m = key_float(segmax[s]);
      const float e = expf(l - m);
      if (s != cur_seg) {
        if (cur_seg >= 0) {
          atomicAdd(&segsum[cur_seg], se);
          atomicAdd(&segwv[cur_seg], sev);
        }
        cur_seg = s;
        se = e;
        sev = e * v;
      } else {
        se += e;
        sev += e * v;
      }
    }
  }
  if (lane == 0 && cur_seg >= 0) {
    atomicAdd(&segsum[cur_seg], se);
    atomicAdd(&segwv[cur_seg], sev);
  }
}

__global__ void final_kernel(const float* __restrict__ segsum,
                             const float* __restrict__ segwv,
                             const float* __restrict__ bo,
                             float* __restrict__ out) {
  const int s = threadIdx.x;
  if (s < NSEG) {
    const float den = segsum[s];
    out[s] = (den > 0.f ? segwv[s] / den : 0.f) + bo[0];
  }
}

extern "C" void kernel_launch(void* const* d_in, const int* in_sizes, int n_in,
                              void* d_out, int out_size, void* d_ws, size_t ws_size,
                              hipStream_t stream) {
  const float* x  = (const float*)d_in[0];
  const int*   sg = (const int*)d_in[1];
  const float* Wk = (const float*)d_in[2];
  const float* bk = (const float*)d_in[3];
  const float* Wv = (const float*)d_in[4];
  const float* bv = (const float*)d_in[5];
  const float* Wo = (const float*)d_in[6];
  const float* bo = (const float*)d_in[7];
  float* out = (float*)d_out;
  const int nrows = in_sizes[1];  // N = number of segment_ids

  float*    ws_vecs = (float*)d_ws;
  unsigned* segmax  = (unsigned*)((char*)d_ws + 4096);
  float*    segsum  = (float*)((char*)d_ws + 4608);
  float*    segwv   = (float*)((char*)d_ws + 5120);
  float*    lbuf    = (float*)((char*)d_ws + 8192);
  float*    vbuf    = lbuf + nrows;

  const size_t need = 8192 + (size_t)nrows * 2 * sizeof(float);
  const bool store = ws_size >= need;

  prep_kernel<<<1, 256, 0, stream>>>(Wk, bk, Wv, bv, Wo, ws_vecs, segmax, segsum, segwv);

  const int rowsPerWave = 64;
  const int nWaves = (nrows + rowsPerWave - 1) / rowsPerWave;
  const int blocks = (nWaves + 3) / 4;  // 4 waves per 256-thread block

  if (store) {
    pass1_kernel<true><<<blocks, 256, 0, stream>>>(x, sg, ws_vecs, lbuf, vbuf,
                                                   segmax, nrows, rowsPerWave);
    pass2_kernel<<<(nrows + 255) / 256, 256, 0, stream>>>(lbuf, vbuf, sg, segmax,
                                                          segsum, segwv, nrows);
  } else {
    pass1_kernel<false><<<blocks, 256, 0, stream>>>(x, sg, ws_vecs, nullptr, nullptr,
                                                    segmax, nrows, rowsPerWave);
    pass2_recompute_kernel<<<blocks, 256, 0, stream>>>(x, sg, ws_vecs, segmax,
                                                       segsum, segwv, nrows, rowsPerWave);
  }

  final_kernel<<<1, 128, 0, stream>>>(segsum, segwv, bo, out);
}

// Round 2
// 779.468 us; speedup vs baseline: 1.0192x; 1.0192x over previous
//
#include <hip/hip_runtime.h>
#include <hip/hip_bf16.h>
#include <math.h>

#define DDIM 256
#define NSEG 128
#define RPW  64   // rows per wave in pass1

// Monotonic uint encoding of float for atomicMax (init 0 is below every key).
__device__ __forceinline__ unsigned float_key(float f) {
  unsigned u = __float_as_uint(f);
  return (u & 0x80000000u) ? ~u : (u | 0x80000000u);
}
__device__ __forceinline__ float key_float(unsigned u) {
  return __uint_as_float((u & 0x80000000u) ? (u & 0x7FFFFFFFu) : ~u);
}

// ws layout (bytes):
//   0    : float ws_vecs[514]  -> wk_sum[256], wvo[256], {bk_sum, bvo}
//   4096 : unsigned segmax[128]
//   4608 : float segsum[128]
//   5120 : float segwv[128]
//   8192 : float lbuf[N]; float vbuf[N]

__global__ __launch_bounds__(256) void prep_kernel(
    const float* __restrict__ Wk, const float* __restrict__ bk,
    const float* __restrict__ Wv, const float* __restrict__ bv,
    const float* __restrict__ Wo,
    float* __restrict__ ws_vecs, unsigned* __restrict__ segmax,
    float* __restrict__ segsum, float* __restrict__ segwv) {
  const int d = threadIdx.x;  // 0..255
  // wk_sum[d] = sum_e Wk[d,e];  wvo[d] = sum_e Wv[d,e]*Wo[e]
  const float4* wkr = (const float4*)(Wk + (size_t)d * DDIM);
  const float4* wvr = (const float4*)(Wv + (size_t)d * DDIM);
  const float4* wo4 = (const float4*)Wo;
  float s1 = 0.f, s2 = 0.f;
  #pragma unroll 4
  for (int e4 = 0; e4 < DDIM / 4; ++e4) {
    float4 a = wkr[e4];
    float4 b = wvr[e4];
    float4 w = wo4[e4];
    s1 += a.x + a.y + a.z + a.w;
    s2 += b.x * w.x + b.y * w.y + b.z * w.z + b.w * w.w;
  }
  ws_vecs[d] = s1;
  ws_vecs[DDIM + d] = s2;

  __shared__ float r1[256], r2[256];
  r1[d] = bk[d];
  r2[d] = bv[d] * Wo[d];
  __syncthreads();
  for (int off = 128; off > 0; off >>= 1) {
    if (d < off) { r1[d] += r1[d + off]; r2[d] += r2[d + off]; }
    __syncthreads();
  }
  if (d == 0) { ws_vecs[2 * DDIM] = r1[0]; ws_vecs[2 * DDIM + 1] = r2[0]; }

  // Re-init accumulators every call (ws re-poisoned 0xAA before each launch)
  if (d < NSEG) { segmax[d] = 0u; segsum[d] = 0.f; segwv[d] = 0.f; }
}

__device__ __forceinline__ void flush_max(int s, float m, unsigned* segmax, int lane) {
  if (s < 0) return;
  #pragma unroll
  for (int off = 32; off; off >>= 1) m = fmaxf(m, __shfl_xor(m, off));
  if (lane == 0) atomicMax(&segmax[s], float_key(m));
}

// Pass 1: quad-per-row. 4 lanes own one row (lane&3 -> 64-col quarter), so a
// wave computes 16 rows per iteration. Reduction = shfl_xor 1,2 (DPP quad ops,
// no LDS pipe). Weights staged in LDS. Per-segment-run max via wave-uniform
// chunk check (seg sorted), one atomicMax per run per wave.
__global__ __launch_bounds__(256) void pass1_kernel(
    const float* __restrict__ x, const int* __restrict__ seg,
    const float* __restrict__ ws_vecs,
    float* __restrict__ lbuf, float* __restrict__ vbuf,
    unsigned* __restrict__ segmax, int nrows) {
  __shared__ float swk[DDIM], swv[DDIM];
  const int tid = threadIdx.x;
  swk[tid] = ws_vecs[tid];
  swv[tid] = ws_vecs[DDIM + tid];
  __syncthreads();
  const float bk_sum = ws_vecs[2 * DDIM];
  const float bvo    = ws_vecs[2 * DDIM + 1];

  const int lane   = tid & 63;
  const int wave   = (blockIdx.x * blockDim.x + tid) >> 6;
  const int sub    = lane & 3;    // column quarter
  const int rowoff = lane >> 2;   // 0..15
  const int row0   = wave * RPW;
  if (row0 >= nrows) return;
  const int row1 = min(row0 + RPW, nrows);

  const float4* swk4 = (const float4*)(swk + sub * 64);
  const float4* swv4 = (const float4*)(swv + sub * 64);

  int   cur_seg = -1;
  float cur_max = -INFINITY;

  for (int c0 = row0; c0 < row1; c0 += 16) {
    const int  row   = c0 + rowoff;
    const bool valid = row < nrows;
    const int  lrow  = valid ? row : nrows - 1;
    const float4* xp = (const float4*)(x + (size_t)lrow * DDIM + sub * 64);
    float dk = 0.f, dv = 0.f;
    #pragma unroll
    for (int j = 0; j < 16; ++j) {
      const float4 x4 = xp[j];
      const float4 a  = swk4[j];
      const float4 b  = swv4[j];
      dk += x4.x * a.x + x4.y * a.y + x4.z * a.z + x4.w * a.w;
      dv += x4.x * b.x + x4.y * b.y + x4.z * b.z + x4.w * b.w;
    }
    dk += __shfl_xor(dk, 1); dk += __shfl_xor(dk, 2);  // quad reduce (DPP)
    dv += __shfl_xor(dv, 1); dv += __shfl_xor(dv, 2);
    const float l = dk + bk_sum;
    if (sub == 0 && valid) { lbuf[row] = l; vbuf[row] = dv + bvo; }

    const int cend    = min(c0 + 15, nrows - 1);
    const int s_first = seg[c0];
    const int s_last  = seg[cend];
    if (s_first == s_last) {           // chunk within one segment (common)
      if (s_first != cur_seg) {
        flush_max(cur_seg, cur_max, segmax, lane);
        cur_seg = s_first;
        cur_max = valid ? l : -INFINITY;
      } else if (valid) {
        cur_max = fmaxf(cur_max, l);
      }
    } else {                           // boundary chunk (rare)
      flush_max(cur_seg, cur_max, segmax, lane);
      cur_seg = -1;
      cur_max = -INFINITY;
      if (sub == 0 && valid) atomicMax(&segmax[seg[row]], float_key(l));
    }
  }
  flush_max(cur_seg, cur_max, segmax, lane);
}

// Pass 2: exp + segmented sums from the l/v buffers (L2-resident, 8 MB).
__global__ __launch_bounds__(256) void pass2_kernel(
    const float* __restrict__ lbuf, const float* __restrict__ vbuf,
    const int* __restrict__ seg, const unsigned* __restrict__ segmax,
    float* __restrict__ segsum, float* __restrict__ segwv, int nrows) {
  const int gid  = blockIdx.x * blockDim.x + threadIdx.x;
  const int lane = threadIdx.x & 63;
  float ex = 0.f, exv = 0.f;
  int s = -1;
  if (gid < nrows) {
    s = seg[gid];
    const float m = key_float(segmax[s]);
    ex  = expf(lbuf[gid] - m);
    exv = ex * vbuf[gid];
  }
  const int  s0  = __shfl(s, 0);
  const bool uni = __all(s == s0);
  if (uni && s0 >= 0) {
    #pragma unroll
    for (int off = 32; off; off >>= 1) {
      ex  += __shfl_xor(ex, off);
      exv += __shfl_xor(exv, off);
    }
    if (lane == 0) {
      atomicAdd(&segsum[s0], ex);
      atomicAdd(&segwv[s0], exv);
    }
  } else if (s >= 0) {
    atomicAdd(&segsum[s], ex);
    atomicAdd(&segwv[s], exv);
  }
}

__global__ void final_kernel(const float* __restrict__ segsum,
                             const float* __restrict__ segwv,
                             const float* __restrict__ bo,
                             float* __restrict__ out) {
  const int s = threadIdx.x;
  if (s < NSEG) {
    const float den = segsum[s];
    out[s] = (den > 0.f ? segwv[s] / den : 0.f) + bo[0];
  }
}

extern "C" void kernel_launch(void* const* d_in, const int* in_sizes, int n_in,
                              void* d_out, int out_size, void* d_ws, size_t ws_size,
                              hipStream_t stream) {
  const float* x  = (const float*)d_in[0];
  const int*   sg = (const int*)d_in[1];
  const float* Wk = (const float*)d_in[2];
  const float* bk = (const float*)d_in[3];
  const float* Wv = (const float*)d_in[4];
  const float* bv = (const float*)d_in[5];
  const float* Wo = (const float*)d_in[6];
  const float* bo = (const float*)d_in[7];
  float* out = (float*)d_out;
  const int nrows = in_sizes[1];  // N

  float*    ws_vecs = (float*)d_ws;
  unsigned* segmax  = (unsigned*)((char*)d_ws + 4096);
  float*    segsum  = (float*)((char*)d_ws + 4608);
  float*    segwv   = (float*)((char*)d_ws + 5120);
  float*    lbuf    = (float*)((char*)d_ws + 8192);
  float*    vbuf    = lbuf + nrows;

  prep_kernel<<<1, 256, 0, stream>>>(Wk, bk, Wv, bv, Wo, ws_vecs, segmax, segsum, segwv);

  const int nWaves = (nrows + RPW - 1) / RPW;
  const int blocks = (nWaves + 3) / 4;  // 4 waves per 256-thread block
  pass1_kernel<<<blocks, 256, 0, stream>>>(x, sg, ws_vecs, lbuf, vbuf, segmax, nrows);
  pass2_kernel<<<(nrows + 255) / 256, 256, 0, stream>>>(lbuf, vbuf, sg, segmax,
                                                        segsum, segwv, nrows);
  final_kernel<<<1, 128, 0, stream>>>(segsum, segwv, bo, out);
}